// Round 7
// baseline (529.503 us; speedup 1.0000x reference)
//
#include <hip/hip_runtime.h>
#include <stdint.h>

#define M_DIM 8192
#define N_DIM 8192
#define K_DIM 1024
#define BK    128

typedef int int4v __attribute__((ext_vector_type(4)));

// ---- async global->LDS, 16B per lane ----
__device__ __forceinline__ void gload16(const char* g, char* l) {
    __builtin_amdgcn_global_load_lds(
        (__attribute__((address_space(1))) void*)(void*)const_cast<char*>(g),
        (__attribute__((address_space(3))) void*)l,
        16, 0, 0);
}

__device__ __forceinline__ int sat8(int v) {
    v = v > 127 ? 127 : v;
    v = v < -128 ? -128 : v;
    return v;
}

// ---- fused pack: blocks [0,8192) pack A; blocks [8192,10240) transpose-pack B ----
__global__ __launch_bounds__(256) void pack_ab_kernel(const int* __restrict__ a,
                                                      const int* __restrict__ b,
                                                      int* __restrict__ outA,
                                                      char* __restrict__ outB) {
    __shared__ char tile[64][68];               // used by B-blocks only
    const int t = threadIdx.x;
    if (blockIdx.x < 8192) {
        // pack a: int32 [M][K] -> int8 [M][K], 4 elems/thread, coalesced
        int i = blockIdx.x * 256 + t;
        int4 v = ((const int4*)a)[i];
        outA[i] = (v.x & 0xff) | ((v.y & 0xff) << 8) |
                  ((v.z & 0xff) << 16) | ((v.w & 0xff) << 24);
        return;
    }
    // pack b: int32 [K][N] -> int8 [N][K] (transpose via LDS tile)
    const int bx = blockIdx.x - 8192;           // 0..2047
    const int n0 = (bx & 127) * 64;
    const int k0 = (bx >> 7) * 64;
    const int tr  = t >> 4;                     // 0..15
    const int tc4 = (t & 15) << 2;              // 0,4,..,60
#pragma unroll
    for (int j = 0; j < 4; ++j) {
        int row = tr + j * 16;                  // k within tile
        int4 v = *(const int4*)&b[(size_t)(k0 + row) * N_DIM + n0 + tc4];
        tile[row][tc4 + 0] = (char)v.x;
        tile[row][tc4 + 1] = (char)v.y;
        tile[row][tc4 + 2] = (char)v.z;
        tile[row][tc4 + 3] = (char)v.w;
    }
    __syncthreads();
#pragma unroll
    for (int j = 0; j < 4; ++j) {
        int n = tr + j * 16;                    // n within tile
        int pk = (tile[tc4 + 0][n] & 0xff) |
                 ((tile[tc4 + 1][n] & 0xff) << 8) |
                 ((tile[tc4 + 2][n] & 0xff) << 16) |
                 ((tile[tc4 + 3][n] & 0xff) << 24);
        *(int*)&outB[(size_t)(n0 + n) * K_DIM + k0 + tc4] = pk;
    }
}

// ---- GEMM (DIAGNOSTIC ROUND): R6 core executed TWICE per dispatch ----
// R0..R6 post-mortem: six independent levers (LDS conflicts, counted-vmcnt
// pipeline, occupancy, MFMA shape, store vectorization, XCD/L2 mapping) ALL
// null at 363-365us total; gemm ~167us invariant, yet every computable pipe
// floor is 35-55us. Model falsified 6x -> buy counters instead of guessing.
// The gemm has never appeared in the top-5 counter table (cutoff ~169us,
// fills ~170-177us). This round reps the whole {K-loop + epilogue} twice in
// one dispatch (acc re-zeroed per rep; C written twice with identical values
// -> idempotent, correctness unaffected; barrier between reps because the
// epilogue repurposes staging LDS). The ~334us dispatch lands on top of the
// profile table and reveals MfmaUtil/VALUBusy/Occupancy/VGPR/FETCH/WRITE/
// conflicts of the true inner loop. Deliberate one-round dur_us cost.
__global__ __launch_bounds__(256) void gemm_i8_kernel(const char* __restrict__ A8,
                                                      const char* __restrict__ B8,
                                                      int* __restrict__ C) {
    // K-loop view: As = smem[0:16K), Bs = smem[16K:32K)  (2 x [k64-half][row][64B])
    // epilogue view: 4 waves x 32x68-int regions = 34816 B
    __shared__ __align__(16) char smem[4 * 8704];
    char* As = smem;
    char* Bs = smem + 16384;

    const int t    = threadIdx.x;
    // XCD-banded, bm-fast mapping (bijective over 4096 = 8 xcd x 8 band x 64 bn)
    const int xcd  = blockIdx.x & 7;
    const int j    = blockIdx.x >> 3;
    const int bm   = (xcd << 3) | (j & 7);
    const int bn   = j >> 3;
    const int lane = t & 63;
    const int wave = t >> 6;
    const int wm   = wave >> 1;                  // 2x2 wave grid, 64x64 per wave
    const int wn   = wave & 1;
    const int quad = lane >> 4;
    const int l16  = lane & 15;

    const size_t aBase = (size_t)(bm * 128) * K_DIM;
    const size_t bBase = (size_t)(bn * 128) * K_DIM;

    // staging: 4 slots/operand/thread, 16 B each
    const int sr = t >> 2;                       // row within 64-row half
    // T2 swizzle (rule 21): source chunk (t&3)^((t>>3)&3), LDS dest linear
    const int swzc = (((t & 3) ^ ((t >> 3) & 3)) << 4);
    // swizzled read chunk byte offset (per-lane constant)
    const int laneByte = ((quad ^ ((l16 >> 1) & 3)) << 4);

#pragma unroll 1
    for (int rep = 0; rep < 2; ++rep) {
        if (rep) __syncthreads();                // epilogue LDS reads done before restage

        int4v acc[4][4] = {};

        for (int kt = 0; kt < K_DIM / BK; ++kt) {
            const int kOff = kt * BK;
#pragma unroll
            for (int s = 0; s < 4; ++s) {
                const int p = s >> 1;                // K64-half
                const int rr = ((s & 1) << 6) + sr;  // tile row
                const int f = s * 4096 + t * 16;     // LDS flat offset (linear dest)
                gload16(A8 + aBase + (size_t)rr * K_DIM + kOff + p * 64 + swzc, As + f);
                gload16(B8 + bBase + (size_t)rr * K_DIM + kOff + p * 64 + swzc, Bs + f);
            }
            __syncthreads();   // drains vmcnt -> staged data visible

#pragma unroll
            for (int h = 0; h < 2; ++h) {            // two K64-halves per stage
                int4v af[4], bf[4];
#pragma unroll
                for (int mi = 0; mi < 4; ++mi)
                    af[mi] = *(const int4v*)
                        &As[h * 8192 + (wm * 64 + mi * 16 + l16) * 64 + laneByte];
#pragma unroll
                for (int ni = 0; ni < 4; ++ni)
                    bf[ni] = *(const int4v*)
                        &Bs[h * 8192 + (wn * 64 + ni * 16 + l16) * 64 + laneByte];

#pragma unroll
                for (int mi = 0; mi < 4; ++mi)
#pragma unroll
                    for (int ni = 0; ni < 4; ++ni)
                        acc[mi][ni] = __builtin_amdgcn_mfma_i32_16x16x64_i8(
                            af[mi], bf[ni], acc[mi][ni], 0, 0, 0);
            }

            __syncthreads();   // LDS reads done before next stage overwrites
        }
        // after final barrier no wave touches As/Bs for the K-loop again; LDS is
        // repurposed per-wave (disjoint regions, no further barrier needed).

        // epilogue: acc (C/D layout: col=l16, row=4*quad+reg) -> per-wave LDS
        // transpose region (32 rows x 68-int padded stride) -> dwordx4 stores.
        int* lw = (int*)(smem + wave * 8704);        // 32*68 ints = 8704 B
        const int mW = bm * 128 + wm * 64;
        const int nW = bn * 128 + wn * 64;
#pragma unroll
        for (int rnd = 0; rnd < 2; ++rnd) {
#pragma unroll
            for (int mh = 0; mh < 2; ++mh) {         // mi = rnd*2 + mh
                const int mi = rnd * 2 + mh;
#pragma unroll
                for (int ni = 0; ni < 4; ++ni)
#pragma unroll
                    for (int r = 0; r < 4; ++r)
                        lw[(mh * 16 + quad * 4 + r) * 68 + ni * 16 + l16] =
                            sat8(acc[mi][ni][r]);
            }
            // same-wave DS ordering: compiler inserts lgkmcnt before dependent reads
#pragma unroll
            for (int rr = 0; rr < 8; ++rr) {
                const int R = rr * 4 + quad;         // local row 0..31
                const int4v v = *(const int4v*)&lw[R * 68 + l16 * 4];
                *(int4v*)&C[(size_t)(mW + rnd * 32 + R) * N_DIM + nW + l16 * 4] = v;
            }
            // round 2 writes ordered after round 1 reads by in-order per-wave DS pipe
        }
    }
}

// ---- fallback (only if ws_size < 16MB): direct int32 GEMM, slow but correct ----
__global__ __launch_bounds__(256) void gemm_naive_kernel(const int* __restrict__ a,
                                                         const int* __restrict__ b,
                                                         int* __restrict__ C) {
    const int col = blockIdx.x * 256 + threadIdx.x;
    const int row = blockIdx.y;
    int acc = 0;
    for (int k = 0; k < K_DIM; ++k)
        acc += a[(size_t)row * K_DIM + k] * b[(size_t)k * N_DIM + col];
    C[(size_t)row * N_DIM + col] = sat8(acc);
}

extern "C" void kernel_launch(void* const* d_in, const int* in_sizes, int n_in,
                              void* d_out, int out_size, void* d_ws, size_t ws_size,
                              hipStream_t stream) {
    const int* a = (const int*)d_in[0];
    const int* b = (const int*)d_in[1];
    // alpha_row (d_in[2]) / alpha_col (d_in[3]) are unused in this variant.
    int* out = (int*)d_out;

    const size_t needed = 2 * (size_t)M_DIM * K_DIM;   // 16 MB packed operands
    if (ws_size < needed) {
        gemm_naive_kernel<<<dim3(N_DIM / 256, M_DIM), 256, 0, stream>>>(a, b, out);
        return;
    }

    char* A8 = (char*)d_ws;                          // 8 MB
    char* B8 = A8 + (size_t)M_DIM * K_DIM;           // 8 MB

    pack_ab_kernel<<<8192 + 2048, 256, 0, stream>>>(a, b, (int*)A8, B8);
    gemm_i8_kernel<<<4096, 256, 0, stream>>>(A8, B8, out);
}

// Round 8
// 367.250 us; speedup vs baseline: 1.4418x; 1.4418x over previous
//
#include <hip/hip_runtime.h>
#include <stdint.h>

#define M_DIM 8192
#define N_DIM 8192
#define K_DIM 1024

typedef int int4v __attribute__((ext_vector_type(4)));

// ---- async global->LDS, 16B per lane ----
__device__ __forceinline__ void gload16(const char* g, char* l) {
    __builtin_amdgcn_global_load_lds(
        (__attribute__((address_space(1))) void*)(void*)const_cast<char*>(g),
        (__attribute__((address_space(3))) void*)l,
        16, 0, 0);
}

__device__ __forceinline__ int sat8(int v) {
    v = v > 127 ? 127 : v;
    v = v < -128 ? -128 : v;
    return v;
}

// ---- fused pack: blocks [0,8192) pack A; blocks [8192,10240) transpose-pack B ----
__global__ __launch_bounds__(256) void pack_ab_kernel(const int* __restrict__ a,
                                                      const int* __restrict__ b,
                                                      int* __restrict__ outA,
                                                      char* __restrict__ outB) {
    __shared__ char tile[64][68];               // used by B-blocks only
    const int t = threadIdx.x;
    if (blockIdx.x < 8192) {
        // pack a: int32 [M][K] -> int8 [M][K], 4 elems/thread, coalesced
        int i = blockIdx.x * 256 + t;
        int4 v = ((const int4*)a)[i];
        outA[i] = (v.x & 0xff) | ((v.y & 0xff) << 8) |
                  ((v.z & 0xff) << 16) | ((v.w & 0xff) << 24);
        return;
    }
    // pack b: int32 [K][N] -> int8 [N][K] (transpose via LDS tile)
    const int bx = blockIdx.x - 8192;           // 0..2047
    const int n0 = (bx & 127) * 64;
    const int k0 = (bx >> 7) * 64;
    const int tr  = t >> 4;                     // 0..15
    const int tc4 = (t & 15) << 2;              // 0,4,..,60
#pragma unroll
    for (int j = 0; j < 4; ++j) {
        int row = tr + j * 16;                  // k within tile
        int4 v = *(const int4*)&b[(size_t)(k0 + row) * N_DIM + n0 + tc4];
        tile[row][tc4 + 0] = (char)v.x;
        tile[row][tc4 + 1] = (char)v.y;
        tile[row][tc4 + 2] = (char)v.z;
        tile[row][tc4 + 3] = (char)v.w;
    }
    __syncthreads();
#pragma unroll
    for (int j = 0; j < 4; ++j) {
        int n = tr + j * 16;                    // n within tile
        int pk = (tile[tc4 + 0][n] & 0xff) |
                 ((tile[tc4 + 1][n] & 0xff) << 8) |
                 ((tile[tc4 + 2][n] & 0xff) << 16) |
                 ((tile[tc4 + 3][n] & 0xff) << 24);
        *(int*)&outB[(size_t)(n0 + n) * K_DIM + k0 + tc4] = pk;
    }
}

// ---- GEMM: 256x256 tile, BK=64, 8 waves (2x4), 3-slot ring, vmcnt(4) ----
// R7 diagnostic (gemm finally profiled): MfmaUtil 20.6%, VALUBusy 9.6%, FETCH
// 37MB (operands cache-resident), bank-conflicts = exactly 1/epilogue-write
// (designed-in free 2-way; K-loop clean). NO pipe saturated -> the binder is
// the {burst-stage -> drain -> short-compute} cadence itself: per K-step the
// MFMA phase (~650 SIMD-cyc/wave) never covers the stage+drain, and 3 desynced
// blocks leave every pipe at 20-40%. R2-R6 all preserved that cadence (6 nulls).
// This round attacks it 3 ways at once: 256^2 tile halves staged bytes/MAC
// (0.0078 vs 0.0156 B/MAC), BK=64 gives a 16-step loop (R1's 8-phase failed at
// 4 steps), and the verified R3 ring (2-deep prefetch, counted vmcnt(4), raw
// s_barrier, never vmcnt(0) in-loop) keeps loads in flight across barriers.
// 1 block/CU (acc=128 VGPR => 2 waves/SIMD); the ring must hide latency
// within the block. Safety: frag ds_reads complete before each wave's MFMAs
// (compiler lgkm wait) which precede the end barrier -> no read crosses into
// the next DMA write; vmcnt(0)+barrier before the epilogue repurposes LDS.
__global__ __launch_bounds__(512, 2) void gemm_i8_kernel(const char* __restrict__ A8,
                                                         const char* __restrict__ B8,
                                                         int* __restrict__ C) {
    __shared__ __align__(16) char As[3][256][64];   // 3 x 16KB K64-slices
    __shared__ __align__(16) char Bs[3][256][64];

    const int t    = threadIdx.x;
    const int bn   = blockIdx.x;
    const int bm   = blockIdx.y;
    const int lane = t & 63;
    const int wave = t >> 6;
    const int wm   = wave >> 2;                  // 0..1 : 128 output rows
    const int wn   = wave & 3;                   // 0..3 : 64 output cols
    const int quad = lane >> 4;
    const int l16  = lane & 15;

    // staging: 2 x 16B chunks per operand per tile per thread (256 rows x 64B)
    // T2 swizzle (rule 21): source chunk (t&3)^((row>>1)&3), row=t>>2; second
    // chunk is row+128 (same mod-4 phase) -> same per-thread constant.
    const int sr   = t >> 2;                     // row 0..127 (i=1 adds 128)
    const int swzc = (((t & 3) ^ ((t >> 3) & 3)) << 4);
    const char* aSrc = A8 + (size_t)(bm * 256) * K_DIM + (size_t)sr * K_DIM + swzc;
    const char* bSrc = B8 + (size_t)(bn * 256) * K_DIM + (size_t)sr * K_DIM + swzc;
    // swizzled read chunk (per-lane constant; frag rows are multiples of 16)
    const int laneByte = ((quad ^ ((l16 >> 1) & 3)) << 4);
    const int aRow = wm * 128 + l16;             // + mi*16
    const int bRow = wn * 64 + l16;              // + ni*16

    int4v acc[8][4] = {};

#define STAGE(TILE, SLOT) do {                                                      \
    const int kOff_ = (TILE) * 64;                                                  \
    gload16(aSrc + kOff_,                        &As[SLOT][0][0] + t * 16);         \
    gload16(aSrc + (size_t)128 * K_DIM + kOff_,  &As[SLOT][0][0] + (t + 512) * 16); \
    gload16(bSrc + kOff_,                        &Bs[SLOT][0][0] + t * 16);         \
    gload16(bSrc + (size_t)128 * K_DIM + kOff_,  &Bs[SLOT][0][0] + (t + 512) * 16); \
} while (0)

    // prologue: tiles 0,1 in flight; retire tile 0 (oldest 4 loads), publish
    STAGE(0, 0);
    STAGE(1, 1);
    asm volatile("s_waitcnt vmcnt(4)" ::: "memory");
    __builtin_amdgcn_s_barrier();
    __builtin_amdgcn_sched_barrier(0);

#pragma unroll 4
    for (int kt = 0; kt < K_DIM / 64; ++kt) {
        const int cur  = kt % 3;
        const int slot = (kt + 2) % 3;
        const int tile = (kt + 2 < K_DIM / 64) ? kt + 2 : K_DIM / 64 - 1;

        int4v af[8], bf[4];
#pragma unroll
        for (int mi = 0; mi < 8; ++mi)
            af[mi] = *(const int4v*)&As[cur][aRow + mi * 16][laneByte];
#pragma unroll
        for (int ni = 0; ni < 4; ++ni)
            bf[ni] = *(const int4v*)&Bs[cur][bRow + ni * 16][laneByte];

        STAGE(tile, slot);                       // lands in 2 K-steps

        __builtin_amdgcn_s_setprio(1);
#pragma unroll
        for (int mi = 0; mi < 8; ++mi)
#pragma unroll
            for (int ni = 0; ni < 4; ++ni)
                acc[mi][ni] = __builtin_amdgcn_mfma_i32_16x16x64_i8(
                    af[mi], bf[ni], acc[mi][ni], 0, 0, 0);
        __builtin_amdgcn_s_setprio(0);

        asm volatile("s_waitcnt vmcnt(4)" ::: "memory");  // next tile resident
        __builtin_amdgcn_s_barrier();
        __builtin_amdgcn_sched_barrier(0);
    }
#undef STAGE

    // drain redundant tail stages, then repurpose LDS for the epilogue
    asm volatile("s_waitcnt vmcnt(0)" ::: "memory");
    __builtin_amdgcn_s_barrier();

    // epilogue: acc (C/D layout: col=l16, row=4*quad+reg) -> per-wave LDS
    // transpose region (32 rows x 68-int padded stride) -> dwordx4 stores.
    // 8 waves x 8704 B = 68 KiB inside the 96 KiB of dead slots.
    int* lw = (int*)(&As[0][0][0] + wave * 8704);
    const int mBase = bm * 256 + wm * 128;
    const int nW    = bn * 256 + wn * 64;
#pragma unroll
    for (int rnd = 0; rnd < 4; ++rnd) {          // 32 output rows per round
#pragma unroll
        for (int mh = 0; mh < 2; ++mh) {         // mi = rnd*2 + mh
            const int mi = rnd * 2 + mh;
#pragma unroll
            for (int ni = 0; ni < 4; ++ni)
#pragma unroll
                for (int r = 0; r < 4; ++r)
                    lw[(mh * 16 + quad * 4 + r) * 68 + ni * 16 + l16] =
                        sat8(acc[mi][ni][r]);
        }
        // same-wave DS ordering: compiler inserts lgkmcnt before dependent reads
#pragma unroll
        for (int rr = 0; rr < 8; ++rr) {
            const int R = rr * 4 + quad;         // local row 0..31
            const int4v v = *(const int4v*)&lw[R * 68 + l16 * 4];
            *(int4v*)&C[(size_t)(mBase + rnd * 32 + R) * N_DIM + nW + l16 * 4] = v;
        }
        // next round's writes ordered after reads by in-order per-wave DS pipe
    }
}

// ---- fallback (only if ws_size < 16MB): direct int32 GEMM, slow but correct ----
__global__ __launch_bounds__(256) void gemm_naive_kernel(const int* __restrict__ a,
                                                         const int* __restrict__ b,
                                                         int* __restrict__ C) {
    const int col = blockIdx.x * 256 + threadIdx.x;
    const int row = blockIdx.y;
    int acc = 0;
    for (int k = 0; k < K_DIM; ++k)
        acc += a[(size_t)row * K_DIM + k] * b[(size_t)k * N_DIM + col];
    C[(size_t)row * N_DIM + col] = sat8(acc);
}

extern "C" void kernel_launch(void* const* d_in, const int* in_sizes, int n_in,
                              void* d_out, int out_size, void* d_ws, size_t ws_size,
                              hipStream_t stream) {
    const int* a = (const int*)d_in[0];
    const int* b = (const int*)d_in[1];
    // alpha_row (d_in[2]) / alpha_col (d_in[3]) are unused in this variant.
    int* out = (int*)d_out;

    const size_t needed = 2 * (size_t)M_DIM * K_DIM;   // 16 MB packed operands
    if (ws_size < needed) {
        gemm_naive_kernel<<<dim3(N_DIM / 256, M_DIM), 256, 0, stream>>>(a, b, out);
        return;
    }

    char* A8 = (char*)d_ws;                          // 8 MB
    char* B8 = A8 + (size_t)M_DIM * K_DIM;           // 8 MB

    pack_ab_kernel<<<8192 + 2048, 256, 0, stream>>>(a, b, (int*)A8, B8);
    gemm_i8_kernel<<<dim3(N_DIM / 256, M_DIM / 256), 512, 0, stream>>>(A8, B8, out);
}